// Round 1
// baseline (249.315 us; speedup 1.0000x reference)
//
#include <hip/hip_runtime.h>
#include <cstdint>
#include <cstddef>

// ---------------------------------------------------------------------------
// SelfAttention (b=4, C=64, 128x128) — MFMA bf16 implementation.
//   q  = Wq@x                      [b,8,16384]
//   kp = maxpool2x2(Wk@x)          [b,8,4096]
//   vp = maxpool2x2(Wv@x)          [b,32,4096]
//   S  = kp^T q  (inner dim 8)     [b,4096,16384], softmax over k (last axis)
//   O  = vp @ softmax(S)           [b,32,16384]
//   y  = gamma * (Wo @ O) + x      [b,64,16384]
//
// Tricks: log2e folded into Kp; -m_f folded into padded K-slots (8,9) of the
// S-MFMA (Q slots 8,9 = 1.0); 1/l_f folded into Vp; C-layout -> B-operand
// transform done in registers with __shfl_xor(.,32) (no LDS round trip).
// ---------------------------------------------------------------------------

#define LOG2E 1.44269504088896340736f

typedef __attribute__((ext_vector_type(8)))  __bf16 bf8_t;
typedef __attribute__((ext_vector_type(8)))  short  s8_t;
typedef __attribute__((ext_vector_type(16))) float  fx16;

__device__ __forceinline__ unsigned short f2bf(float f) {
  unsigned int u = __builtin_bit_cast(unsigned int, f);
  u += 0x7FFFu + ((u >> 16) & 1u);   // round-nearest-even
  return (unsigned short)(u >> 16);
}
__device__ __forceinline__ float bf2f(unsigned short h) {
  unsigned int u = ((unsigned int)h) << 16;
  return __builtin_bit_cast(float, u);
}
__device__ __forceinline__ unsigned int pk2(unsigned short lo, unsigned short hi) {
  return (unsigned int)lo | ((unsigned int)hi << 16);
}

#if __has_builtin(__builtin_amdgcn_exp2f)
#define EXP2F __builtin_amdgcn_exp2f
#else
#define EXP2F exp2f
#endif

// ------------------------------- K1a: Q pack -------------------------------
// thread per (b,k). Writes Q' [b*16384+k][16] bf16: rows 0..7 = q, 8,9 = 1.0.
__global__ void __launch_bounds__(256) k_qpack(const float* __restrict__ x,
                                               const float* __restrict__ Wq,
                                               unsigned short* __restrict__ Qp) {
  __shared__ float w[512];
  int t = threadIdx.x;
  for (int i = t; i < 512; i += 256) w[i] = Wq[i];
  __syncthreads();
  int gid = blockIdx.x * 256 + t;                 // b*16384 + k
  const float* xp = x + ((size_t)(gid >> 14) * 64 * 16384) + (gid & 16383);
  float q[8];
#pragma unroll
  for (int o = 0; o < 8; ++o) q[o] = 0.f;
  for (int c = 0; c < 64; ++c) {
    float xv = xp[(size_t)c * 16384];
#pragma unroll
    for (int o = 0; o < 8; ++o) q[o] += w[o * 64 + c] * xv;
  }
  unsigned short q16[16];
#pragma unroll
  for (int o = 0; o < 8; ++o) q16[o] = f2bf(q[o]);
  q16[8] = 0x3F80u; q16[9] = 0x3F80u;             // 1.0 slots (receive -m)
#pragma unroll
  for (int i = 10; i < 16; ++i) q16[i] = 0;
  uint4* dst = reinterpret_cast<uint4*>(Qp + (size_t)gid * 16);
  uint4 a, b2;
  a.x = pk2(q16[0], q16[1]);  a.y = pk2(q16[2], q16[3]);
  a.z = pk2(q16[4], q16[5]);  a.w = pk2(q16[6], q16[7]);
  b2.x = pk2(q16[8], q16[9]); b2.y = pk2(q16[10], q16[11]);
  b2.z = pk2(q16[12], q16[13]); b2.w = pk2(q16[14], q16[15]);
  dst[0] = a; dst[1] = b2;
}

// ------------------------- K1b: K/V conv + maxpool -------------------------
// thread per (b, f, pos): conv at one of the 4 spatial positions of pooled
// cell f, then max-reduce over the 4 lanes (shfl_xor 1,2).
__global__ void __launch_bounds__(256) k_kvpool(const float* __restrict__ x,
                                                const float* __restrict__ Wk,
                                                const float* __restrict__ Wv,
                                                float* __restrict__ Kp,
                                                unsigned short* __restrict__ KpB,
                                                float* __restrict__ Vp) {
  __shared__ float wk[64][8];    // [c][o]
  __shared__ float wv[64][32];   // [c][o]
  int t = threadIdx.x;
  for (int i = t; i < 512; i += 256)  wk[i & 63][i >> 6] = Wk[i];
  for (int i = t; i < 2048; i += 256) wv[i & 63][i >> 6] = Wv[i];
  __syncthreads();
  int gid = blockIdx.x * 256 + t;                 // b*16384 + f*4 + pos
  int b = gid >> 14, r = gid & 16383;
  int f = r >> 2, pos = r & 3;
  int p0 = ((f >> 6) << 1) | (pos >> 1);
  int p1 = ((f & 63) << 1) | (pos & 1);
  const float* xp = x + (size_t)b * 64 * 16384 + p0 * 128 + p1;
  float kc[8], vc[32];
#pragma unroll
  for (int o = 0; o < 8; ++o) kc[o] = 0.f;
#pragma unroll
  for (int o = 0; o < 32; ++o) vc[o] = 0.f;
  for (int c = 0; c < 64; ++c) {
    float xv = xp[(size_t)c * 16384];
#pragma unroll
    for (int o = 0; o < 8; ++o) kc[o] += wk[c][o] * xv;
#pragma unroll
    for (int o = 0; o < 32; ++o) vc[o] += wv[c][o] * xv;
  }
#pragma unroll
  for (int o = 0; o < 8; ++o) {
    kc[o] = fmaxf(kc[o], __shfl_xor(kc[o], 1));
    kc[o] = fmaxf(kc[o], __shfl_xor(kc[o], 2));
  }
#pragma unroll
  for (int o = 0; o < 32; ++o) {
    vc[o] = fmaxf(vc[o], __shfl_xor(vc[o], 1));
    vc[o] = fmaxf(vc[o], __shfl_xor(vc[o], 2));
  }
  if (pos == 0) {
    size_t idx = (size_t)b * 4096 + f;
    float* kd = Kp + idx * 8;
#pragma unroll
    for (int o = 0; o < 8; ++o) kd[o] = kc[o];
    unsigned short* kb = KpB + idx * 16;
#pragma unroll
    for (int o = 0; o < 8; ++o) kb[o] = f2bf(kc[o] * LOG2E);
#pragma unroll
    for (int o = 8; o < 16; ++o) kb[o] = 0;
    float* vd = Vp + idx * 32;
#pragma unroll
    for (int o = 0; o < 32; ++o) vd[o] = vc[o];
  }
}

// ----------------------------- K2: row stats -------------------------------
// block = (b, fgroup of 32), 4 waves split k. Sweep 1: max; sweep 2: sum exp2.
// S already log2e-scaled via KpB. Wave-local (m,l) combined through LDS.
__global__ void __launch_bounds__(256) k_stats(const unsigned short* __restrict__ Qp,
                                               const unsigned short* __restrict__ KpB,
                                               float* __restrict__ Ms,
                                               float* __restrict__ Ls) {
  int b = blockIdx.x >> 7, fg = blockIdx.x & 127;
  int wv = threadIdx.x >> 6, lane = threadIdx.x & 63;
  int half = lane >> 5, l31 = lane & 31;
  bf8_t A = *reinterpret_cast<const bf8_t*>(
      KpB + ((size_t)(b * 4096 + fg * 32 + l31) * 16 + half * 8));
  const unsigned short* qbase =
      Qp + ((size_t)b * 16384 + (size_t)wv * 4096) * 16 + half * 8;
  fx16 z;
#pragma unroll
  for (int i = 0; i < 16; ++i) z[i] = 0.f;
  float m[16];
#pragma unroll
  for (int i = 0; i < 16; ++i) m[i] = -3.0e38f;
  for (int tt = 0; tt < 128; ++tt) {
    bf8_t B = *reinterpret_cast<const bf8_t*>(qbase + (size_t)(tt * 32 + l31) * 16);
    fx16 s = __builtin_amdgcn_mfma_f32_32x32x16_bf16(A, B, z, 0, 0, 0);
#pragma unroll
    for (int r0 = 0; r0 < 16; ++r0) m[r0] = fmaxf(m[r0], s[r0]);
  }
#pragma unroll
  for (int r0 = 0; r0 < 16; ++r0)
    for (int d = 1; d < 32; d <<= 1) m[r0] = fmaxf(m[r0], __shfl_xor(m[r0], d));
  float l[16];
#pragma unroll
  for (int i = 0; i < 16; ++i) l[i] = 0.f;
  for (int tt = 0; tt < 128; ++tt) {
    bf8_t B = *reinterpret_cast<const bf8_t*>(qbase + (size_t)(tt * 32 + l31) * 16);
    fx16 s = __builtin_amdgcn_mfma_f32_32x32x16_bf16(A, B, z, 0, 0, 0);
#pragma unroll
    for (int r0 = 0; r0 < 16; ++r0) l[r0] += EXP2F(s[r0] - m[r0]);
  }
#pragma unroll
  for (int r0 = 0; r0 < 16; ++r0)
    for (int d = 1; d < 32; d <<= 1) l[r0] += __shfl_xor(l[r0], d);
  __shared__ float sm[4][32], sl[4][32];
  if (l31 == 0) {
#pragma unroll
    for (int r0 = 0; r0 < 16; ++r0) {
      int row = (r0 & 3) + 8 * (r0 >> 2) + 4 * half;
      sm[wv][row] = m[r0];
      sl[wv][row] = l[r0];
    }
  }
  __syncthreads();
  if (threadIdx.x < 32) {
    int fl = threadIdx.x;
    float M = sm[0][fl];
#pragma unroll
    for (int w2 = 1; w2 < 4; ++w2) M = fmaxf(M, sm[w2][fl]);
    float L = 0.f;
#pragma unroll
    for (int w2 = 0; w2 < 4; ++w2) L += sl[w2][fl] * EXP2F(sm[w2][fl] - M);
    size_t idx = (size_t)b * 4096 + fg * 32 + fl;
    Ms[idx] = M;
    Ls[idx] = L;
  }
}

// ------------------------------ K3: pack -----------------------------------
// Kp' [f][16] bf16: rows0-7 = Kp*log2e, slot8/9 = bf16 split of -M, rest 0.
// Vp' [c][f] bf16 = Vp / L.  Block 64 packs Wo -> bf16 [o][c].
__global__ void __launch_bounds__(256) k_pack(const float* __restrict__ Kp,
                                              const float* __restrict__ Vp,
                                              const float* __restrict__ Ms,
                                              const float* __restrict__ Ls,
                                              const float* __restrict__ Wo,
                                              unsigned short* __restrict__ Kpp,
                                              unsigned short* __restrict__ Vpp,
                                              unsigned short* __restrict__ Wop) {
  if (blockIdx.x == 64) {
    for (int i = threadIdx.x; i < 2048; i += 256) Wop[i] = f2bf(Wo[i]);
    return;
  }
  int gid = blockIdx.x * 256 + threadIdx.x;       // b*4096 + f
  float M = Ms[gid], L = Ls[gid];
  float rl = 1.0f / L;
  const float* kp = Kp + (size_t)gid * 8;
  unsigned short o16[16];
#pragma unroll
  for (int i = 0; i < 8; ++i) o16[i] = f2bf(kp[i] * LOG2E);
  unsigned short mh = f2bf(-M);
  o16[8] = mh;
  o16[9] = f2bf(-M - bf2f(mh));                   // residual for extra precision
#pragma unroll
  for (int i = 10; i < 16; ++i) o16[i] = 0;
  uint4* dst = reinterpret_cast<uint4*>(Kpp + (size_t)gid * 16);
  uint4 a, b2;
  a.x = pk2(o16[0], o16[1]);  a.y = pk2(o16[2], o16[3]);
  a.z = pk2(o16[4], o16[5]);  a.w = pk2(o16[6], o16[7]);
  b2.x = pk2(o16[8], o16[9]); b2.y = pk2(o16[10], o16[11]);
  b2.z = pk2(o16[12], o16[13]); b2.w = pk2(o16[14], o16[15]);
  dst[0] = a; dst[1] = b2;
  int b = gid >> 12, f = gid & 4095;
  const float* vp = Vp + (size_t)gid * 32;
#pragma unroll
  for (int c = 0; c < 32; ++c)
    Vpp[((size_t)b * 32 + c) * 4096 + f] = f2bf(vp[c] * rl);
}

// C-layout (8 regs = rows {0-3,8-11}+4*half) -> B-operand bf16 frag via
// lane^32 exchange. Verified mapping: row(r) = (r&3)+8*(r>>2)+4*(lane>>5).
__device__ __forceinline__ bf8_t c2b(const float* p, int half) {
  float t[8];
#pragma unroll
  for (int i = 0; i < 8; ++i) t[i] = __shfl_xor(p[i], 32);
  s8_t v;
#pragma unroll
  for (int j = 0; j < 4; ++j) {
    v[j]     = (short)f2bf(half ? t[j + 4] : p[j]);
    v[j + 4] = (short)f2bf(half ? p[j + 4] : t[j]);
  }
  return __builtin_bit_cast(bf8_t, v);
}

// ------------------------- K4: attention + project --------------------------
// wave per 32-k subtile; loop f in chunks of 32:
//   S = mfma(Kp', Q')  (already exp2-ready, -m folded)
//   P = exp2(S); c2b -> 2 B-frags; O += mfma(Vp', P) x2
// epilogue: O -> B-frags, Y = Wo' @ O (2 o-tiles x 2 c-chunks), y = g*Y + x.
__global__ void __launch_bounds__(256) k_attn(const unsigned short* __restrict__ Qp,
                                              const unsigned short* __restrict__ Kpp,
                                              const unsigned short* __restrict__ Vpp,
                                              const unsigned short* __restrict__ Wop,
                                              const float* __restrict__ x,
                                              const float* __restrict__ gamma,
                                              float* __restrict__ out) {
  int b = blockIdx.x >> 7, kt = blockIdx.x & 127;
  int wv = threadIdx.x >> 6, lane = threadIdx.x & 63;
  int half = lane >> 5, l31 = lane & 31;
  int k = kt * 128 + wv * 32 + l31;
  bf8_t Bq = *reinterpret_cast<const bf8_t*>(
      Qp + ((size_t)(b * 16384 + k) * 16 + half * 8));
  fx16 z;
#pragma unroll
  for (int i = 0; i < 16; ++i) z[i] = 0.f;
  fx16 acc = z;
  const unsigned short* kpB = Kpp + ((size_t)b * 4096 + l31) * 16 + half * 8;
  const unsigned short* vpB = Vpp + ((size_t)(b * 32 + l31)) * 4096 + half * 8;
  for (int fc = 0; fc < 128; ++fc) {
    int f0 = fc * 32;
    bf8_t Ak = *reinterpret_cast<const bf8_t*>(kpB + (size_t)f0 * 16);
    fx16 s = __builtin_amdgcn_mfma_f32_32x32x16_bf16(Ak, Bq, z, 0, 0, 0);
    float p[16];
#pragma unroll
    for (int r0 = 0; r0 < 16; ++r0) p[r0] = EXP2F(s[r0]);
    bf8_t Pb0 = c2b(p, half);
    bf8_t Pb1 = c2b(p + 8, half);
    bf8_t Av0 = *reinterpret_cast<const bf8_t*>(vpB + f0);
    bf8_t Av1 = *reinterpret_cast<const bf8_t*>(vpB + f0 + 16);
    acc = __builtin_amdgcn_mfma_f32_32x32x16_bf16(Av0, Pb0, acc, 0, 0, 0);
    acc = __builtin_amdgcn_mfma_f32_32x32x16_bf16(Av1, Pb1, acc, 0, 0, 0);
  }
  float oc[16];
#pragma unroll
  for (int i = 0; i < 16; ++i) oc[i] = acc[i];
  bf8_t Ob0 = c2b(oc, half);
  bf8_t Ob1 = c2b(oc + 8, half);
  bf8_t Aw00 = *reinterpret_cast<const bf8_t*>(Wop + l31 * 32 + half * 8);
  bf8_t Aw01 = *reinterpret_cast<const bf8_t*>(Wop + l31 * 32 + 16 + half * 8);
  bf8_t Aw10 = *reinterpret_cast<const bf8_t*>(Wop + (l31 + 32) * 32 + half * 8);
  bf8_t Aw11 = *reinterpret_cast<const bf8_t*>(Wop + (l31 + 32) * 32 + 16 + half * 8);
  fx16 y0 = __builtin_amdgcn_mfma_f32_32x32x16_bf16(Aw00, Ob0, z, 0, 0, 0);
  y0 = __builtin_amdgcn_mfma_f32_32x32x16_bf16(Aw01, Ob1, y0, 0, 0, 0);
  fx16 y1 = __builtin_amdgcn_mfma_f32_32x32x16_bf16(Aw10, Ob0, z, 0, 0, 0);
  y1 = __builtin_amdgcn_mfma_f32_32x32x16_bf16(Aw11, Ob1, y1, 0, 0, 0);
  float g = gamma[0];
  const float* xp = x + (size_t)b * 64 * 16384 + k;
  float* op = out + (size_t)b * 64 * 16384 + k;
#pragma unroll
  for (int r0 = 0; r0 < 16; ++r0) {
    int row = (r0 & 3) + 8 * (r0 >> 2) + 4 * half;
    op[(size_t)row * 16384] = g * y0[r0] + xp[(size_t)row * 16384];
    op[(size_t)(row + 32) * 16384] = g * y1[r0] + xp[(size_t)(row + 32) * 16384];
  }
}

// ---------------------------------------------------------------------------
extern "C" void kernel_launch(void* const* d_in, const int* in_sizes, int n_in,
                              void* d_out, int out_size, void* d_ws, size_t ws_size,
                              hipStream_t stream) {
  const float* x     = (const float*)d_in[0];
  const float* Wq    = (const float*)d_in[1];
  const float* Wk    = (const float*)d_in[2];
  const float* Wv    = (const float*)d_in[3];
  const float* Wo    = (const float*)d_in[4];
  const float* gamma = (const float*)d_in[5];
  float* out = (float*)d_out;
  char* ws = (char*)d_ws;
  // workspace layout (bytes)
  unsigned short* Qp  = (unsigned short*)(ws + 0);        // 4*16384*16*2 = 2 MB
  unsigned short* KpB = (unsigned short*)(ws + 2097152);  // 512 KB
  unsigned short* Kpp = (unsigned short*)(ws + 2621440);  // 512 KB
  float*          Kp  = (float*)(ws + 3145728);           // 512 KB
  float*          Vp  = (float*)(ws + 3670016);           // 2 MB
  unsigned short* Vpp = (unsigned short*)(ws + 5767168);  // 1 MB
  float*          Ms  = (float*)(ws + 6815744);           // 64 KB
  float*          Ls  = (float*)(ws + 6881280);           // 64 KB
  unsigned short* Wop = (unsigned short*)(ws + 6946816);  // 4 KB

  k_qpack<<<dim3(256), dim3(256), 0, stream>>>(x, Wq, Qp);
  k_kvpool<<<dim3(256), dim3(256), 0, stream>>>(x, Wk, Wv, Kp, KpB, Vp);
  k_stats<<<dim3(512), dim3(256), 0, stream>>>(Qp, KpB, Ms, Ls);
  k_pack<<<dim3(65), dim3(256), 0, stream>>>(Kp, Vp, Ms, Ls, Wo, Kpp, Vpp, Wop);
  k_attn<<<dim3(512), dim3(256), 0, stream>>>(Qp, Kpp, Vpp, Wop, x, gamma, out);
}

// Round 2
// 214.617 us; speedup vs baseline: 1.1617x; 1.1617x over previous
//
#include <hip/hip_runtime.h>
#include <cstdint>
#include <cstddef>

// ---------------------------------------------------------------------------
// SelfAttention (b=4, C=64, 128x128) — MFMA bf16, round 2.
//   S = kp^T q (inner 8, padded to 16), softmax over k WITHOUT max pass
//   (|S| < ~45 by Xavier-scale argument; exp2 in fp32 is safe to 2^127).
//   l[f] = sum_k exp2(S2[f,k]);  Vp' = Vp/l (bf16, f-permuted);
//   O = Vp' @ exp2(S2);  y = gamma*(Wo' @ O) + x.
// The C/D->B-operand layout transform is absorbed into a static column
// permutation pi (involution: [0-3][8-11][4-7][12-15] per 16-group) applied
// to Vp's f-columns and Wo's c-columns at pack time -> NO shuffles in k_attn.
// ---------------------------------------------------------------------------

#define LOG2E 1.44269504088896340736f

typedef __attribute__((ext_vector_type(8)))  __bf16 bf8_t;
typedef __attribute__((ext_vector_type(16))) float  fx16;

__device__ __forceinline__ unsigned short f2bf(float f) {
  unsigned int u = __builtin_bit_cast(unsigned int, f);
  u += 0x7FFFu + ((u >> 16) & 1u);   // round-nearest-even
  return (unsigned short)(u >> 16);
}
__device__ __forceinline__ unsigned int pk2(unsigned short lo, unsigned short hi) {
  return (unsigned int)lo | ((unsigned int)hi << 16);
}
// involution permutation on a 16-group: swap middle two quads
__device__ __forceinline__ int pi16(int s) {
  int m = (s >> 2) & 3;
  return (m == 1 || m == 2) ? (s ^ 12) : s;
}

#if __has_builtin(__builtin_amdgcn_exp2f)
#define EXP2F __builtin_amdgcn_exp2f
#else
#define EXP2F exp2f
#endif

// ----------------------- K1: fused q/k/v (one x pass) -----------------------
// thread per (b, f, pos). Computes q[8] for its own position (always written),
// k[8]/v[32] conv then 2x2 maxpool via shfl_xor(1,2); lane pos==0 writes
// KpB (bf16, *log2e, padded to 16 with zeros) and Vp (fp32).
__global__ void __launch_bounds__(256) k_qkv(const float* __restrict__ x,
                                             const float* __restrict__ Wq,
                                             const float* __restrict__ Wk,
                                             const float* __restrict__ Wv,
                                             unsigned short* __restrict__ Qp,
                                             unsigned short* __restrict__ KpB,
                                             float* __restrict__ Vp) {
  __shared__ float wq[64][8], wk[64][8], wv[64][32];
  int t = threadIdx.x;
  for (int i = t; i < 512; i += 256) {
    wq[i & 63][i >> 6] = Wq[i];
    wk[i & 63][i >> 6] = Wk[i];
  }
  for (int i = t; i < 2048; i += 256) wv[i & 63][i >> 6] = Wv[i];
  __syncthreads();
  int gid = blockIdx.x * 256 + t;                 // b*16384 + f*4 + pos
  int b = gid >> 14, r = gid & 16383, f = r >> 2, pos = r & 3;
  int p0 = ((f >> 6) << 1) | (pos >> 1);
  int p1 = ((f & 63) << 1) | (pos & 1);
  int k = p0 * 128 + p1;
  const float* xp = x + (size_t)b * (64 * 16384) + k;
  float q[8], kc[8], vc[32];
#pragma unroll
  for (int o = 0; o < 8; ++o) { q[o] = 0.f; kc[o] = 0.f; }
#pragma unroll
  for (int o = 0; o < 32; ++o) vc[o] = 0.f;
  for (int c = 0; c < 64; ++c) {
    float xv = xp[(size_t)c * 16384];
#pragma unroll
    for (int o = 0; o < 8; ++o) { q[o] += wq[c][o] * xv; kc[o] += wk[c][o] * xv; }
#pragma unroll
    for (int o = 0; o < 32; ++o) vc[o] += wv[c][o] * xv;
  }
  // Q' write: 8 bf16 + 8 zeros
  unsigned short q16[8];
#pragma unroll
  for (int o = 0; o < 8; ++o) q16[o] = f2bf(q[o]);
  uint4 qa, z4;
  qa.x = pk2(q16[0], q16[1]); qa.y = pk2(q16[2], q16[3]);
  qa.z = pk2(q16[4], q16[5]); qa.w = pk2(q16[6], q16[7]);
  z4.x = z4.y = z4.z = z4.w = 0u;
  uint4* qdst = reinterpret_cast<uint4*>(Qp + ((size_t)b * 16384 + k) * 16);
  qdst[0] = qa; qdst[1] = z4;
  // 2x2 maxpool across the 4 pos-lanes
#pragma unroll
  for (int o = 0; o < 8; ++o) {
    kc[o] = fmaxf(kc[o], __shfl_xor(kc[o], 1));
    kc[o] = fmaxf(kc[o], __shfl_xor(kc[o], 2));
  }
#pragma unroll
  for (int o = 0; o < 32; ++o) {
    vc[o] = fmaxf(vc[o], __shfl_xor(vc[o], 1));
    vc[o] = fmaxf(vc[o], __shfl_xor(vc[o], 2));
  }
  if (pos == 0) {
    size_t idx = (size_t)b * 4096 + f;
    unsigned short k16[8];
#pragma unroll
    for (int o = 0; o < 8; ++o) k16[o] = f2bf(kc[o] * LOG2E);
    uint4 ka;
    ka.x = pk2(k16[0], k16[1]); ka.y = pk2(k16[2], k16[3]);
    ka.z = pk2(k16[4], k16[5]); ka.w = pk2(k16[6], k16[7]);
    uint4* kdst = reinterpret_cast<uint4*>(KpB + idx * 16);
    kdst[0] = ka; kdst[1] = z4;
    float4* vdst = reinterpret_cast<float4*>(Vp + idx * 32);
#pragma unroll
    for (int j = 0; j < 8; ++j)
      vdst[j] = make_float4(vc[4 * j], vc[4 * j + 1], vc[4 * j + 2], vc[4 * j + 3]);
  }
}

// --------------------------- K2: l = sum exp2(S2) ---------------------------
// block = (b, f-tile of 32); 4 waves split k into quarters. Single sweep.
__global__ void __launch_bounds__(256) k_lsum(const unsigned short* __restrict__ Qp,
                                              const unsigned short* __restrict__ KpB,
                                              float* __restrict__ Ls) {
  int b = blockIdx.x >> 7, fg = blockIdx.x & 127;
  int wv = threadIdx.x >> 6, lane = threadIdx.x & 63;
  int half = lane >> 5, l31 = lane & 31;
  bf8_t A = *reinterpret_cast<const bf8_t*>(
      KpB + ((size_t)(b * 4096 + fg * 32 + l31)) * 16 + half * 8);
  const unsigned short* qbase =
      Qp + ((size_t)b * 16384 + (size_t)wv * 4096) * 16 + half * 8;
  fx16 z;
#pragma unroll
  for (int i = 0; i < 16; ++i) z[i] = 0.f;
  float l[16];
#pragma unroll
  for (int i = 0; i < 16; ++i) l[i] = 0.f;
  for (int tt = 0; tt < 128; ++tt) {
    bf8_t B = *reinterpret_cast<const bf8_t*>(qbase + (size_t)(tt * 32 + l31) * 16);
    fx16 s = __builtin_amdgcn_mfma_f32_32x32x16_bf16(A, B, z, 0, 0, 0);
#pragma unroll
    for (int r0 = 0; r0 < 16; ++r0) l[r0] += EXP2F(s[r0]);
  }
#pragma unroll
  for (int r0 = 0; r0 < 16; ++r0)
    for (int d = 1; d < 32; d <<= 1) l[r0] += __shfl_xor(l[r0], d);
  __shared__ float sl[4][32];
  if (l31 == 0) {
#pragma unroll
    for (int r0 = 0; r0 < 16; ++r0) {
      int row = (r0 & 3) + 8 * (r0 >> 2) + 4 * half;
      sl[wv][row] = l[r0];
    }
  }
  __syncthreads();
  if (threadIdx.x < 32) {
    int fl = threadIdx.x;
    float L = sl[0][fl] + sl[1][fl] + sl[2][fl] + sl[3][fl];
    Ls[(size_t)b * 4096 + fg * 32 + fl] = L;
  }
}

// ------------------------------ K3: pack -----------------------------------
// Vpp[b][c][f'] bf16 = Vp[b][pi(f)][c] / l[pi(f)]  (pi per 16-group of f).
// Block 64 packs Wo -> bf16 with pi on c-columns (per 16-group).
__global__ void __launch_bounds__(256) k_pack(const float* __restrict__ Vp,
                                              const float* __restrict__ Ls,
                                              const float* __restrict__ Wo,
                                              unsigned short* __restrict__ Vpp,
                                              unsigned short* __restrict__ Wop) {
  if (blockIdx.x == 64) {
    for (int i = threadIdx.x; i < 2048; i += 256) {
      int c = i & 31;
      Wop[i] = f2bf(Wo[(i & ~31) | (c & 16) | pi16(c & 15)]);
    }
    return;
  }
  int b = blockIdx.x >> 4, f0 = (blockIdx.x & 15) * 256;
  __shared__ unsigned short T[32][264];            // +8 pad, rows 16B-aligned
  int t = threadIdx.x;
  float rl = 1.0f / Ls[(size_t)b * 4096 + f0 + t];
  const float* vp = Vp + ((size_t)b * 4096 + f0 + t) * 32;
  int fl = (t & ~15) | pi16(t & 15);               // destination column (involution)
  for (int c = 0; c < 32; ++c) T[c][fl] = f2bf(vp[c] * rl);
  __syncthreads();
  for (int u = t; u < 1024; u += 256) {            // 32 rows x 32 uint4
    int row = u >> 5, e0 = (u & 31) * 8;
    uint4 val = *reinterpret_cast<const uint4*>(&T[row][e0]);
    *reinterpret_cast<uint4*>(Vpp + ((size_t)b * 32 + row) * 4096 + f0 + e0) = val;
  }
}

// ------------------------- K4: attention + project --------------------------
// wave per 32-k subtile; loop f in chunks of 32:
//   S2 = mfma(KpB, Q'); P = exp2(S2) -> direct bitcast to B frags (Vpp is
//   f-permuted); O += mfma(Vpp, P) x2. Epilogue: Y = Wop @ O (c-permuted),
//   y = g*Y + x. No cross-lane ops anywhere.
__global__ void __launch_bounds__(256) k_attn(const unsigned short* __restrict__ Qp,
                                              const unsigned short* __restrict__ KpB,
                                              const unsigned short* __restrict__ Vpp,
                                              const unsigned short* __restrict__ Wop,
                                              const float* __restrict__ x,
                                              const float* __restrict__ gamma,
                                              float* __restrict__ out) {
  int b = blockIdx.x >> 7, kt = blockIdx.x & 127;
  int wv = threadIdx.x >> 6, lane = threadIdx.x & 63;
  int half = lane >> 5, l31 = lane & 31;
  int k = kt * 128 + wv * 32 + l31;
  bf8_t Bq = *reinterpret_cast<const bf8_t*>(
      Qp + ((size_t)b * 16384 + k) * 16 + half * 8);
  fx16 z;
#pragma unroll
  for (int i = 0; i < 16; ++i) z[i] = 0.f;
  fx16 acc = z;
  const unsigned short* kpB = KpB + ((size_t)b * 4096 + l31) * 16 + half * 8;
  const unsigned short* vpB = Vpp + ((size_t)(b * 32 + l31)) * 4096 + half * 8;
  bf8_t Ak  = *reinterpret_cast<const bf8_t*>(kpB);
  bf8_t Av0 = *reinterpret_cast<const bf8_t*>(vpB);
  bf8_t Av1 = *reinterpret_cast<const bf8_t*>(vpB + 16);
  for (int fc = 0; fc < 128; ++fc) {
    int f1 = ((fc + 1) & 127) * 32;                // wraps; branch-free prefetch
    bf8_t nAk  = *reinterpret_cast<const bf8_t*>(kpB + (size_t)f1 * 16);
    bf8_t nAv0 = *reinterpret_cast<const bf8_t*>(vpB + f1);
    bf8_t nAv1 = *reinterpret_cast<const bf8_t*>(vpB + f1 + 16);
    fx16 s = __builtin_amdgcn_mfma_f32_32x32x16_bf16(Ak, Bq, z, 0, 0, 0);
    bf8_t Pb0, Pb1;
#pragma unroll
    for (int j = 0; j < 8; ++j) Pb0[j] = (__bf16)EXP2F(s[j]);
#pragma unroll
    for (int j = 0; j < 8; ++j) Pb1[j] = (__bf16)EXP2F(s[8 + j]);
    acc = __builtin_amdgcn_mfma_f32_32x32x16_bf16(Av0, Pb0, acc, 0, 0, 0);
    acc = __builtin_amdgcn_mfma_f32_32x32x16_bf16(Av1, Pb1, acc, 0, 0, 0);
    Ak = nAk; Av0 = nAv0; Av1 = nAv1;
  }
  bf8_t Ob0, Ob1;
#pragma unroll
  for (int j = 0; j < 8; ++j) { Ob0[j] = (__bf16)acc[j]; Ob1[j] = (__bf16)acc[8 + j]; }
  const unsigned short* wb = Wop + l31 * 32 + half * 8;
  bf8_t Aw00 = *reinterpret_cast<const bf8_t*>(wb);
  bf8_t Aw01 = *reinterpret_cast<const bf8_t*>(wb + 16);
  bf8_t Aw10 = *reinterpret_cast<const bf8_t*>(wb + 1024);
  bf8_t Aw11 = *reinterpret_cast<const bf8_t*>(wb + 1024 + 16);
  fx16 y0 = __builtin_amdgcn_mfma_f32_32x32x16_bf16(Aw00, Ob0, z, 0, 0, 0);
  y0 = __builtin_amdgcn_mfma_f32_32x32x16_bf16(Aw01, Ob1, y0, 0, 0, 0);
  fx16 y1 = __builtin_amdgcn_mfma_f32_32x32x16_bf16(Aw10, Ob0, z, 0, 0, 0);
  y1 = __builtin_amdgcn_mfma_f32_32x32x16_bf16(Aw11, Ob1, y1, 0, 0, 0);
  float g = gamma[0];
  const float* xp = x + (size_t)b * 64 * 16384 + k;
  float* op = out + (size_t)b * 64 * 16384 + k;
#pragma unroll
  for (int r0 = 0; r0 < 16; ++r0) {
    int row = (r0 & 3) + 8 * (r0 >> 2) + 4 * half;
    op[(size_t)row * 16384]        = fmaf(g, y0[r0], xp[(size_t)row * 16384]);
    op[(size_t)(row + 32) * 16384] = fmaf(g, y1[r0], xp[(size_t)(row + 32) * 16384]);
  }
}

// ---------------------------------------------------------------------------
extern "C" void kernel_launch(void* const* d_in, const int* in_sizes, int n_in,
                              void* d_out, int out_size, void* d_ws, size_t ws_size,
                              hipStream_t stream) {
  const float* x     = (const float*)d_in[0];
  const float* Wq    = (const float*)d_in[1];
  const float* Wk    = (const float*)d_in[2];
  const float* Wv    = (const float*)d_in[3];
  const float* Wo    = (const float*)d_in[4];
  const float* gamma = (const float*)d_in[5];
  float* out = (float*)d_out;
  char* ws = (char*)d_ws;
  // workspace layout (bytes)
  unsigned short* Qp  = (unsigned short*)(ws + 0);        // 2 MB
  unsigned short* KpB = (unsigned short*)(ws + 2097152);  // 512 KB
  float*          Vp  = (float*)(ws + 2621440);           // 2 MB
  unsigned short* Vpp = (unsigned short*)(ws + 4718592);  // 1 MB
  float*          Ls  = (float*)(ws + 5767168);           // 64 KB
  unsigned short* Wop = (unsigned short*)(ws + 5832704);  // 4 KB

  k_qkv <<<dim3(256), dim3(256), 0, stream>>>(x, Wq, Wk, Wv, Qp, KpB, Vp);
  k_lsum<<<dim3(512), dim3(256), 0, stream>>>(Qp, KpB, Ls);
  k_pack<<<dim3(65),  dim3(256), 0, stream>>>(Vp, Ls, Wo, Vpp, Wop);
  k_attn<<<dim3(512), dim3(256), 0, stream>>>(Qp, KpB, Vpp, Wop, x, gamma, out);
}

// Round 3
// 190.631 us; speedup vs baseline: 1.3078x; 1.1258x over previous
//
#include <hip/hip_runtime.h>
#include <cstdint>
#include <cstddef>

// ---------------------------------------------------------------------------
// SelfAttention (b=4, C=64, 128x128) — MFMA bf16, round 3.
// Same math as round 2 (no-max softmax, pi-permuted Vpp/Wop so the MFMA
// C-layout feeds the next MFMA's B-operand by direct bitcast).
// Round-3 change: full-occupancy restructure.
//   k_attn: block = one 32-k tile, 4 waves split f 4-ways, LDS-reduce the
//           partial O accumulators, waves 0/1 do the Wo epilogue.
//           grid 2048 -> 8 blocks/CU -> 32 waves/CU (was 8).
//   k_lsum: block = 1024 thr (16 waves) splitting k 16-ways, LDS-reduce.
//           grid 512 -> 2 blocks/CU -> 32 waves/CU.
// ---------------------------------------------------------------------------

#define LOG2E 1.44269504088896340736f

typedef __attribute__((ext_vector_type(8)))  __bf16 bf8_t;
typedef __attribute__((ext_vector_type(16))) float  fx16;

__device__ __forceinline__ unsigned short f2bf(float f) {
  unsigned int u = __builtin_bit_cast(unsigned int, f);
  u += 0x7FFFu + ((u >> 16) & 1u);   // round-nearest-even
  return (unsigned short)(u >> 16);
}
__device__ __forceinline__ unsigned int pk2(unsigned short lo, unsigned short hi) {
  return (unsigned int)lo | ((unsigned int)hi << 16);
}
// involution permutation on a 16-group: swap middle two quads
__device__ __forceinline__ int pi16(int s) {
  int m = (s >> 2) & 3;
  return (m == 1 || m == 2) ? (s ^ 12) : s;
}

#if __has_builtin(__builtin_amdgcn_exp2f)
#define EXP2F __builtin_amdgcn_exp2f
#else
#define EXP2F exp2f
#endif

// ----------------------- K1: fused q/k/v (one x pass) -----------------------
__global__ void __launch_bounds__(256) k_qkv(const float* __restrict__ x,
                                             const float* __restrict__ Wq,
                                             const float* __restrict__ Wk,
                                             const float* __restrict__ Wv,
                                             unsigned short* __restrict__ Qp,
                                             unsigned short* __restrict__ KpB,
                                             float* __restrict__ Vp) {
  __shared__ float wq[64][8], wk[64][8], wv[64][32];
  int t = threadIdx.x;
  for (int i = t; i < 512; i += 256) {
    wq[i & 63][i >> 6] = Wq[i];
    wk[i & 63][i >> 6] = Wk[i];
  }
  for (int i = t; i < 2048; i += 256) wv[i & 63][i >> 6] = Wv[i];
  __syncthreads();
  int gid = blockIdx.x * 256 + t;                 // b*16384 + f*4 + pos
  int b = gid >> 14, r = gid & 16383, f = r >> 2, pos = r & 3;
  int p0 = ((f >> 6) << 1) | (pos >> 1);
  int p1 = ((f & 63) << 1) | (pos & 1);
  int k = p0 * 128 + p1;
  const float* xp = x + (size_t)b * (64 * 16384) + k;
  float q[8], kc[8], vc[32];
#pragma unroll
  for (int o = 0; o < 8; ++o) { q[o] = 0.f; kc[o] = 0.f; }
#pragma unroll
  for (int o = 0; o < 32; ++o) vc[o] = 0.f;
  for (int c = 0; c < 64; ++c) {
    float xv = xp[(size_t)c * 16384];
    const float4* q4 = reinterpret_cast<const float4*>(&wq[c][0]);
    const float4* k4 = reinterpret_cast<const float4*>(&wk[c][0]);
    const float4* v4 = reinterpret_cast<const float4*>(&wv[c][0]);
#pragma unroll
    for (int j = 0; j < 2; ++j) {
      float4 a = q4[j], bq = k4[j];
      q[4 * j]      += a.x * xv; q[4 * j + 1]  += a.y * xv;
      q[4 * j + 2]  += a.z * xv; q[4 * j + 3]  += a.w * xv;
      kc[4 * j]     += bq.x * xv; kc[4 * j + 1] += bq.y * xv;
      kc[4 * j + 2] += bq.z * xv; kc[4 * j + 3] += bq.w * xv;
    }
#pragma unroll
    for (int j = 0; j < 8; ++j) {
      float4 a = v4[j];
      vc[4 * j]     += a.x * xv; vc[4 * j + 1] += a.y * xv;
      vc[4 * j + 2] += a.z * xv; vc[4 * j + 3] += a.w * xv;
    }
  }
  unsigned short q16[8];
#pragma unroll
  for (int o = 0; o < 8; ++o) q16[o] = f2bf(q[o]);
  uint4 qa, z4;
  qa.x = pk2(q16[0], q16[1]); qa.y = pk2(q16[2], q16[3]);
  qa.z = pk2(q16[4], q16[5]); qa.w = pk2(q16[6], q16[7]);
  z4.x = z4.y = z4.z = z4.w = 0u;
  uint4* qdst = reinterpret_cast<uint4*>(Qp + ((size_t)b * 16384 + k) * 16);
  qdst[0] = qa; qdst[1] = z4;
#pragma unroll
  for (int o = 0; o < 8; ++o) {
    kc[o] = fmaxf(kc[o], __shfl_xor(kc[o], 1));
    kc[o] = fmaxf(kc[o], __shfl_xor(kc[o], 2));
  }
#pragma unroll
  for (int o = 0; o < 32; ++o) {
    vc[o] = fmaxf(vc[o], __shfl_xor(vc[o], 1));
    vc[o] = fmaxf(vc[o], __shfl_xor(vc[o], 2));
  }
  if (pos == 0) {
    size_t idx = (size_t)b * 4096 + f;
    unsigned short k16[8];
#pragma unroll
    for (int o = 0; o < 8; ++o) k16[o] = f2bf(kc[o] * LOG2E);
    uint4 ka;
    ka.x = pk2(k16[0], k16[1]); ka.y = pk2(k16[2], k16[3]);
    ka.z = pk2(k16[4], k16[5]); ka.w = pk2(k16[6], k16[7]);
    uint4* kdst = reinterpret_cast<uint4*>(KpB + idx * 16);
    kdst[0] = ka; kdst[1] = z4;
    float4* vdst = reinterpret_cast<float4*>(Vp + idx * 32);
#pragma unroll
    for (int j = 0; j < 8; ++j)
      vdst[j] = make_float4(vc[4 * j], vc[4 * j + 1], vc[4 * j + 2], vc[4 * j + 3]);
  }
}

// --------------------------- K2: l = sum exp2(S2) ---------------------------
// block = 1024 thr (16 waves) per (b, f-tile of 32); waves split k 16-ways.
__global__ void __launch_bounds__(1024) k_lsum(const unsigned short* __restrict__ Qp,
                                               const unsigned short* __restrict__ KpB,
                                               float* __restrict__ Ls) {
  int b = blockIdx.x >> 7, fg = blockIdx.x & 127;
  int wv = threadIdx.x >> 6, lane = threadIdx.x & 63;
  int half = lane >> 5, l31 = lane & 31;
  bf8_t A = *reinterpret_cast<const bf8_t*>(
      KpB + ((size_t)(b * 4096 + fg * 32 + l31)) * 16 + half * 8);
  const unsigned short* qbase = Qp + ((size_t)b * 16384) * 16 + half * 8;
  fx16 z;
#pragma unroll
  for (int i = 0; i < 16; ++i) z[i] = 0.f;
  float l[16];
#pragma unroll
  for (int i = 0; i < 16; ++i) l[i] = 0.f;
  for (int i = 0; i < 32; ++i) {
    int tt = wv * 32 + i;                          // chunk of 32 k
    bf8_t B = *reinterpret_cast<const bf8_t*>(qbase + (size_t)(tt * 32 + l31) * 16);
    fx16 s = __builtin_amdgcn_mfma_f32_32x32x16_bf16(A, B, z, 0, 0, 0);
#pragma unroll
    for (int r0 = 0; r0 < 16; ++r0) l[r0] += EXP2F(s[r0]);
  }
#pragma unroll
  for (int r0 = 0; r0 < 16; ++r0)
    for (int d = 1; d < 32; d <<= 1) l[r0] += __shfl_xor(l[r0], d);
  __shared__ float sl[16][32];
  if (l31 == 0) {
#pragma unroll
    for (int r0 = 0; r0 < 16; ++r0) {
      int row = (r0 & 3) + 8 * (r0 >> 2) + 4 * half;
      sl[wv][row] = l[r0];
    }
  }
  __syncthreads();
  if (threadIdx.x < 32) {
    int fl = threadIdx.x;
    float L = 0.f;
#pragma unroll
    for (int w2 = 0; w2 < 16; ++w2) L += sl[w2][fl];
    Ls[(size_t)b * 4096 + fg * 32 + fl] = L;
  }
}

// ------------------------------ K3: pack -----------------------------------
__global__ void __launch_bounds__(256) k_pack(const float* __restrict__ Vp,
                                              const float* __restrict__ Ls,
                                              const float* __restrict__ Wo,
                                              unsigned short* __restrict__ Vpp,
                                              unsigned short* __restrict__ Wop) {
  if (blockIdx.x == 64) {
    for (int i = threadIdx.x; i < 2048; i += 256) {
      int c = i & 31;
      Wop[i] = f2bf(Wo[(i & ~31) | (c & 16) | pi16(c & 15)]);
    }
    return;
  }
  int b = blockIdx.x >> 4, f0 = (blockIdx.x & 15) * 256;
  __shared__ unsigned short T[32][264];            // +8 pad, rows 16B-aligned
  int t = threadIdx.x;
  float rl = 1.0f / Ls[(size_t)b * 4096 + f0 + t];
  const float* vp = Vp + ((size_t)b * 4096 + f0 + t) * 32;
  int fl = (t & ~15) | pi16(t & 15);               // destination column (involution)
  for (int c = 0; c < 32; ++c) T[c][fl] = f2bf(vp[c] * rl);
  __syncthreads();
  for (int u = t; u < 1024; u += 256) {            // 32 rows x 32 uint4
    int row = u >> 5, e0 = (u & 31) * 8;
    uint4 val = *reinterpret_cast<const uint4*>(&T[row][e0]);
    *reinterpret_cast<uint4*>(Vpp + ((size_t)b * 32 + row) * 4096 + f0 + e0) = val;
  }
}

// ------------------------- K4: attention + project --------------------------
// block = one 32-k tile; 4 waves split f (32 chunks of 32 each). Partial O
// accs LDS-reduced; waves 0/1 apply Wo for o-tiles 0/1 and write y=g*Y+x.
__global__ void __launch_bounds__(256) k_attn(const unsigned short* __restrict__ Qp,
                                              const unsigned short* __restrict__ KpB,
                                              const unsigned short* __restrict__ Vpp,
                                              const unsigned short* __restrict__ Wop,
                                              const float* __restrict__ x,
                                              const float* __restrict__ gamma,
                                              float* __restrict__ out) {
  int b = blockIdx.x >> 9, kt = blockIdx.x & 511;
  int wv = threadIdx.x >> 6, lane = threadIdx.x & 63;
  int half = lane >> 5, l31 = lane & 31;
  int k = kt * 32 + l31;
  bf8_t Bq = *reinterpret_cast<const bf8_t*>(
      Qp + ((size_t)b * 16384 + k) * 16 + half * 8);
  fx16 z;
#pragma unroll
  for (int i = 0; i < 16; ++i) z[i] = 0.f;
  fx16 acc = z;
  const unsigned short* kpB = KpB + ((size_t)b * 4096 + l31) * 16 + half * 8;
  const unsigned short* vpB = Vpp + ((size_t)(b * 32 + l31)) * 4096 + half * 8;
  int c0 = wv * 32;                                // wave's first f-chunk
  int f0 = c0 * 32;
  bf8_t Ak  = *reinterpret_cast<const bf8_t*>(kpB + (size_t)f0 * 16);
  bf8_t Av0 = *reinterpret_cast<const bf8_t*>(vpB + f0);
  bf8_t Av1 = *reinterpret_cast<const bf8_t*>(vpB + f0 + 16);
  for (int fc = 0; fc < 32; ++fc) {
    int f1 = ((c0 + fc + 1) & 127) * 32;           // wraps; branch-free prefetch
    bf8_t nAk  = *reinterpret_cast<const bf8_t*>(kpB + (size_t)f1 * 16);
    bf8_t nAv0 = *reinterpret_cast<const bf8_t*>(vpB + f1);
    bf8_t nAv1 = *reinterpret_cast<const bf8_t*>(vpB + f1 + 16);
    fx16 s = __builtin_amdgcn_mfma_f32_32x32x16_bf16(Ak, Bq, z, 0, 0, 0);
    bf8_t Pb0, Pb1;
#pragma unroll
    for (int j = 0; j < 8; ++j) Pb0[j] = (__bf16)EXP2F(s[j]);
#pragma unroll
    for (int j = 0; j < 8; ++j) Pb1[j] = (__bf16)EXP2F(s[8 + j]);
    acc = __builtin_amdgcn_mfma_f32_32x32x16_bf16(Av0, Pb0, acc, 0, 0, 0);
    acc = __builtin_amdgcn_mfma_f32_32x32x16_bf16(Av1, Pb1, acc, 0, 0, 0);
    Ak = nAk; Av0 = nAv0; Av1 = nAv1;
  }
  __shared__ float sacc[4][64][16];
#pragma unroll
  for (int j = 0; j < 16; ++j) sacc[wv][lane][j] = acc[j];
  __syncthreads();
  if (wv >= 2) return;
  fx16 tot;
#pragma unroll
  for (int j = 0; j < 16; ++j)
    tot[j] = (sacc[0][lane][j] + sacc[1][lane][j]) +
             (sacc[2][lane][j] + sacc[3][lane][j]);
  bf8_t Ob0, Ob1;
#pragma unroll
  for (int j = 0; j < 8; ++j) { Ob0[j] = (__bf16)tot[j]; Ob1[j] = (__bf16)tot[8 + j]; }
  const unsigned short* wb = Wop + (wv * 32 + l31) * 32 + half * 8;
  bf8_t Aw0 = *reinterpret_cast<const bf8_t*>(wb);
  bf8_t Aw1 = *reinterpret_cast<const bf8_t*>(wb + 16);
  fx16 y = __builtin_amdgcn_mfma_f32_32x32x16_bf16(Aw0, Ob0, z, 0, 0, 0);
  y = __builtin_amdgcn_mfma_f32_32x32x16_bf16(Aw1, Ob1, y, 0, 0, 0);
  float g = gamma[0];
  const float* xp = x + (size_t)b * 64 * 16384 + k;
  float* op = out + (size_t)b * 64 * 16384 + k;
#pragma unroll
  for (int r0 = 0; r0 < 16; ++r0) {
    int row = (r0 & 3) + 8 * (r0 >> 2) + 4 * half + wv * 32;
    op[(size_t)row * 16384] = fmaf(g, y[r0], xp[(size_t)row * 16384]);
  }
}

// ---------------------------------------------------------------------------
extern "C" void kernel_launch(void* const* d_in, const int* in_sizes, int n_in,
                              void* d_out, int out_size, void* d_ws, size_t ws_size,
                              hipStream_t stream) {
  const float* x     = (const float*)d_in[0];
  const float* Wq    = (const float*)d_in[1];
  const float* Wk    = (const float*)d_in[2];
  const float* Wv    = (const float*)d_in[3];
  const float* Wo    = (const float*)d_in[4];
  const float* gamma = (const float*)d_in[5];
  float* out = (float*)d_out;
  char* ws = (char*)d_ws;
  // workspace layout (bytes)
  unsigned short* Qp  = (unsigned short*)(ws + 0);        // 2 MB
  unsigned short* KpB = (unsigned short*)(ws + 2097152);  // 512 KB
  float*          Vp  = (float*)(ws + 2621440);           // 2 MB
  unsigned short* Vpp = (unsigned short*)(ws + 4718592);  // 1 MB
  float*          Ls  = (float*)(ws + 5767168);           // 64 KB
  unsigned short* Wop = (unsigned short*)(ws + 5832704);  // 4 KB

  k_qkv <<<dim3(256),  dim3(256),  0, stream>>>(x, Wq, Wk, Wv, Qp, KpB, Vp);
  k_lsum<<<dim3(512),  dim3(1024), 0, stream>>>(Qp, KpB, Ls);
  k_pack<<<dim3(65),   dim3(256),  0, stream>>>(Vp, Ls, Wo, Vpp, Wop);
  k_attn<<<dim3(2048), dim3(256),  0, stream>>>(Qp, KpB, Vpp, Wop, x, gamma, out);
}

// Round 4
// 168.025 us; speedup vs baseline: 1.4838x; 1.1345x over previous
//
#include <hip/hip_runtime.h>
#include <cstdint>
#include <cstddef>

// ---------------------------------------------------------------------------
// SelfAttention (b=4, C=64, 128x128) — MFMA bf16, round 4.
// Math unchanged from round 2/3 (no-max softmax; pi-permuted Vpp/Wop so the
// MFMA C-layout feeds the next MFMA's B-operand by direct bitcast).
// Round-4: work amortization per wave (stalls, not occupancy, were binding).
//   k_attn: KB=2 k-tiles per wave — 2 Bq frags + 2 accs share each K/V
//           fragment load (L2 traffic halved, 2 independent MFMA chains).
//           Conflict-free f4-vectorized LDS reduction; all 4 waves do the
//           (ktile, otile) epilogue.
//   k_lsum: FB=2 f-groups per block — each Q fragment load feeds 2 MFMAs.
// ---------------------------------------------------------------------------

#define LOG2E 1.44269504088896340736f

typedef __attribute__((ext_vector_type(8)))  __bf16 bf8_t;
typedef __attribute__((ext_vector_type(16))) float  fx16;

__device__ __forceinline__ unsigned short f2bf(float f) {
  unsigned int u = __builtin_bit_cast(unsigned int, f);
  u += 0x7FFFu + ((u >> 16) & 1u);   // round-nearest-even
  return (unsigned short)(u >> 16);
}
__device__ __forceinline__ unsigned int pk2(unsigned short lo, unsigned short hi) {
  return (unsigned int)lo | ((unsigned int)hi << 16);
}
// involution permutation on a 16-group: swap middle two quads
__device__ __forceinline__ int pi16(int s) {
  int m = (s >> 2) & 3;
  return (m == 1 || m == 2) ? (s ^ 12) : s;
}

#if __has_builtin(__builtin_amdgcn_exp2f)
#define EXP2F __builtin_amdgcn_exp2f
#else
#define EXP2F exp2f
#endif

// ----------------------- K1: fused q/k/v (one x pass) -----------------------
__global__ void __launch_bounds__(256) k_qkv(const float* __restrict__ x,
                                             const float* __restrict__ Wq,
                                             const float* __restrict__ Wk,
                                             const float* __restrict__ Wv,
                                             unsigned short* __restrict__ Qp,
                                             unsigned short* __restrict__ KpB,
                                             float* __restrict__ Vp) {
  __shared__ float wq[64][8], wk[64][8], wv[64][32];
  int t = threadIdx.x;
  for (int i = t; i < 512; i += 256) {
    wq[i & 63][i >> 6] = Wq[i];
    wk[i & 63][i >> 6] = Wk[i];
  }
  for (int i = t; i < 2048; i += 256) wv[i & 63][i >> 6] = Wv[i];
  __syncthreads();
  int gid = blockIdx.x * 256 + t;                 // b*16384 + f*4 + pos
  int b = gid >> 14, r = gid & 16383, f = r >> 2, pos = r & 3;
  int p0 = ((f >> 6) << 1) | (pos >> 1);
  int p1 = ((f & 63) << 1) | (pos & 1);
  int k = p0 * 128 + p1;
  const float* xp = x + (size_t)b * (64 * 16384) + k;
  float q[8], kc[8], vc[32];
#pragma unroll
  for (int o = 0; o < 8; ++o) { q[o] = 0.f; kc[o] = 0.f; }
#pragma unroll
  for (int o = 0; o < 32; ++o) vc[o] = 0.f;
  for (int c = 0; c < 64; ++c) {
    float xv = xp[(size_t)c * 16384];
    const float4* q4 = reinterpret_cast<const float4*>(&wq[c][0]);
    const float4* k4 = reinterpret_cast<const float4*>(&wk[c][0]);
    const float4* v4 = reinterpret_cast<const float4*>(&wv[c][0]);
#pragma unroll
    for (int j = 0; j < 2; ++j) {
      float4 a = q4[j], bq = k4[j];
      q[4 * j]      += a.x * xv; q[4 * j + 1]  += a.y * xv;
      q[4 * j + 2]  += a.z * xv; q[4 * j + 3]  += a.w * xv;
      kc[4 * j]     += bq.x * xv; kc[4 * j + 1] += bq.y * xv;
      kc[4 * j + 2] += bq.z * xv; kc[4 * j + 3] += bq.w * xv;
    }
#pragma unroll
    for (int j = 0; j < 8; ++j) {
      float4 a = v4[j];
      vc[4 * j]     += a.x * xv; vc[4 * j + 1] += a.y * xv;
      vc[4 * j + 2] += a.z * xv; vc[4 * j + 3] += a.w * xv;
    }
  }
  unsigned short q16[8];
#pragma unroll
  for (int o = 0; o < 8; ++o) q16[o] = f2bf(q[o]);
  uint4 qa, z4;
  qa.x = pk2(q16[0], q16[1]); qa.y = pk2(q16[2], q16[3]);
  qa.z = pk2(q16[4], q16[5]); qa.w = pk2(q16[6], q16[7]);
  z4.x = z4.y = z4.z = z4.w = 0u;
  uint4* qdst = reinterpret_cast<uint4*>(Qp + ((size_t)b * 16384 + k) * 16);
  qdst[0] = qa; qdst[1] = z4;
#pragma unroll
  for (int o = 0; o < 8; ++o) {
    kc[o] = fmaxf(kc[o], __shfl_xor(kc[o], 1));
    kc[o] = fmaxf(kc[o], __shfl_xor(kc[o], 2));
  }
#pragma unroll
  for (int o = 0; o < 32; ++o) {
    vc[o] = fmaxf(vc[o], __shfl_xor(vc[o], 1));
    vc[o] = fmaxf(vc[o], __shfl_xor(vc[o], 2));
  }
  if (pos == 0) {
    size_t idx = (size_t)b * 4096 + f;
    unsigned short k16[8];
#pragma unroll
    for (int o = 0; o < 8; ++o) k16[o] = f2bf(kc[o] * LOG2E);
    uint4 ka;
    ka.x = pk2(k16[0], k16[1]); ka.y = pk2(k16[2], k16[3]);
    ka.z = pk2(k16[4], k16[5]); ka.w = pk2(k16[6], k16[7]);
    uint4* kdst = reinterpret_cast<uint4*>(KpB + idx * 16);
    kdst[0] = ka; kdst[1] = z4;
    float4* vdst = reinterpret_cast<float4*>(Vp + idx * 32);
#pragma unroll
    for (int j = 0; j < 8; ++j)
      vdst[j] = make_float4(vc[4 * j], vc[4 * j + 1], vc[4 * j + 2], vc[4 * j + 3]);
  }
}

// --------------------------- K2: l = sum exp2(S2) ---------------------------
// block = 1024 thr (16 waves) per (b, f-group pair of 64 rows); each wave
// owns a 1024-k slice; one Q fragment load feeds 2 MFMAs (FB=2).
__global__ void __launch_bounds__(1024) k_lsum(const unsigned short* __restrict__ Qp,
                                               const unsigned short* __restrict__ KpB,
                                               float* __restrict__ Ls) {
  int b = blockIdx.x >> 6, g = blockIdx.x & 63;
  int wv = threadIdx.x >> 6, lane = threadIdx.x & 63;
  int half = lane >> 5, l31 = lane & 31;
  const unsigned short* kb =
      KpB + ((size_t)(b * 4096 + g * 64 + l31)) * 16 + half * 8;
  bf8_t A0 = *reinterpret_cast<const bf8_t*>(kb);
  bf8_t A1 = *reinterpret_cast<const bf8_t*>(kb + 32 * 16);
  const unsigned short* qbase = Qp + ((size_t)b * 16384) * 16 + half * 8;
  fx16 z;
#pragma unroll
  for (int i = 0; i < 16; ++i) z[i] = 0.f;
  float l[32];
#pragma unroll
  for (int i = 0; i < 32; ++i) l[i] = 0.f;
  int t0 = wv * 32;                                // wave's first 32-k chunk
  bf8_t B = *reinterpret_cast<const bf8_t*>(qbase + (size_t)(t0 * 32 + l31) * 16);
  for (int i = 0; i < 32; ++i) {
    int tn = t0 + ((i + 1) & 31);
    bf8_t nB = *reinterpret_cast<const bf8_t*>(qbase + (size_t)(tn * 32 + l31) * 16);
    fx16 s0 = __builtin_amdgcn_mfma_f32_32x32x16_bf16(A0, B, z, 0, 0, 0);
    fx16 s1 = __builtin_amdgcn_mfma_f32_32x32x16_bf16(A1, B, z, 0, 0, 0);
#pragma unroll
    for (int r0 = 0; r0 < 16; ++r0) l[r0] += EXP2F(s0[r0]);
#pragma unroll
    for (int r0 = 0; r0 < 16; ++r0) l[16 + r0] += EXP2F(s1[r0]);
    B = nB;
  }
#pragma unroll
  for (int r0 = 0; r0 < 32; ++r0)
    for (int d = 1; d < 32; d <<= 1) l[r0] += __shfl_xor(l[r0], d);
  __shared__ float sl[16][2][32];
  if (l31 == 0) {
#pragma unroll
    for (int r0 = 0; r0 < 16; ++r0) {
      int row = (r0 & 3) + 8 * (r0 >> 2) + 4 * half;
      sl[wv][0][row] = l[r0];
      sl[wv][1][row] = l[16 + r0];
    }
  }
  __syncthreads();
  if (threadIdx.x < 64) {
    int fgi = threadIdx.x >> 5, row = threadIdx.x & 31;
    float L = 0.f;
#pragma unroll
    for (int w2 = 0; w2 < 16; ++w2) L += sl[w2][fgi][row];
    Ls[(size_t)b * 4096 + g * 64 + fgi * 32 + row] = L;
  }
}

// ------------------------------ K3: pack -----------------------------------
__global__ void __launch_bounds__(256) k_pack(const float* __restrict__ Vp,
                                              const float* __restrict__ Ls,
                                              const float* __restrict__ Wo,
                                              unsigned short* __restrict__ Vpp,
                                              unsigned short* __restrict__ Wop) {
  if (blockIdx.x == 64) {
    for (int i = threadIdx.x; i < 2048; i += 256) {
      int c = i & 31;
      Wop[i] = f2bf(Wo[(i & ~31) | (c & 16) | pi16(c & 15)]);
    }
    return;
  }
  int b = blockIdx.x >> 4, f0 = (blockIdx.x & 15) * 256;
  __shared__ unsigned short T[32][264];            // +8 pad, rows 16B-aligned
  int t = threadIdx.x;
  float rl = 1.0f / Ls[(size_t)b * 4096 + f0 + t];
  const float* vp = Vp + ((size_t)b * 4096 + f0 + t) * 32;
  int fl = (t & ~15) | pi16(t & 15);               // destination column (involution)
  for (int c = 0; c < 32; ++c) T[c][fl] = f2bf(vp[c] * rl);
  __syncthreads();
  for (int u = t; u < 1024; u += 256) {            // 32 rows x 32 uint4
    int row = u >> 5, e0 = (u & 31) * 8;
    uint4 val = *reinterpret_cast<const uint4*>(&T[row][e0]);
    *reinterpret_cast<uint4*>(Vpp + ((size_t)b * 32 + row) * 4096 + f0 + e0) = val;
  }
}

// ------------------------- K4: attention + project --------------------------
// block = one 64-k pair of tiles; 4 waves split f 4-ways, each wave carries
// KB=2 (Bq0/Bq1, acc0/acc1) so every K/V fragment load feeds 6 MFMAs.
// LDS-reduce (lane-major float4, conflict-free), wave wv does the epilogue
// for ktile=wv&1, otile=wv>>1.
__global__ void __launch_bounds__(256) k_attn(const unsigned short* __restrict__ Qp,
                                              const unsigned short* __restrict__ KpB,
                                              const unsigned short* __restrict__ Vpp,
                                              const unsigned short* __restrict__ Wop,
                                              const float* __restrict__ x,
                                              const float* __restrict__ gamma,
                                              float* __restrict__ out) {
  int b = blockIdx.x >> 8, kp = blockIdx.x & 255;
  int wv = threadIdx.x >> 6, lane = threadIdx.x & 63;
  int half = lane >> 5, l31 = lane & 31;
  int kbase = kp * 64;
  const unsigned short* qb = Qp + ((size_t)b * 16384 + kbase + l31) * 16 + half * 8;
  bf8_t Bq0 = *reinterpret_cast<const bf8_t*>(qb);
  bf8_t Bq1 = *reinterpret_cast<const bf8_t*>(qb + 32 * 16);
  fx16 z;
#pragma unroll
  for (int i = 0; i < 16; ++i) z[i] = 0.f;
  fx16 acc0 = z, acc1 = z;
  const unsigned short* kpB = KpB + ((size_t)b * 4096 + l31) * 16 + half * 8;
  const unsigned short* vpB = Vpp + ((size_t)(b * 32 + l31)) * 4096 + half * 8;
  int c0 = wv * 32;                                // wave's first f-chunk
  int f0 = c0 * 32;
  bf8_t Ak  = *reinterpret_cast<const bf8_t*>(kpB + (size_t)f0 * 16);
  bf8_t Av0 = *reinterpret_cast<const bf8_t*>(vpB + f0);
  bf8_t Av1 = *reinterpret_cast<const bf8_t*>(vpB + f0 + 16);
  for (int fc = 0; fc < 32; ++fc) {
    int f1 = (c0 + ((fc + 1) & 31)) * 32;          // wraps within wave's range
    bf8_t nAk  = *reinterpret_cast<const bf8_t*>(kpB + (size_t)f1 * 16);
    bf8_t nAv0 = *reinterpret_cast<const bf8_t*>(vpB + f1);
    bf8_t nAv1 = *reinterpret_cast<const bf8_t*>(vpB + f1 + 16);
    fx16 s0 = __builtin_amdgcn_mfma_f32_32x32x16_bf16(Ak, Bq0, z, 0, 0, 0);
    fx16 s1 = __builtin_amdgcn_mfma_f32_32x32x16_bf16(Ak, Bq1, z, 0, 0, 0);
    bf8_t P00, P01, P10, P11;
#pragma unroll
    for (int j = 0; j < 8; ++j) {
      P00[j] = (__bf16)EXP2F(s0[j]);
      P01[j] = (__bf16)EXP2F(s0[8 + j]);
    }
#pragma unroll
    for (int j = 0; j < 8; ++j) {
      P10[j] = (__bf16)EXP2F(s1[j]);
      P11[j] = (__bf16)EXP2F(s1[8 + j]);
    }
    acc0 = __builtin_amdgcn_mfma_f32_32x32x16_bf16(Av0, P00, acc0, 0, 0, 0);
    acc1 = __builtin_amdgcn_mfma_f32_32x32x16_bf16(Av0, P10, acc1, 0, 0, 0);
    acc0 = __builtin_amdgcn_mfma_f32_32x32x16_bf16(Av1, P01, acc0, 0, 0, 0);
    acc1 = __builtin_amdgcn_mfma_f32_32x32x16_bf16(Av1, P11, acc1, 0, 0, 0);
    Ak = nAk; Av0 = nAv0; Av1 = nAv1;
  }
  // lane-major reduction buffer: [wv][kt][j4][lane][4] -> conflict-free f4
  __shared__ float sacc[4][2][4][64][4];
#pragma unroll
  for (int j4 = 0; j4 < 4; ++j4) {
    *reinterpret_cast<float4*>(&sacc[wv][0][j4][lane][0]) =
        make_float4(acc0[4 * j4], acc0[4 * j4 + 1], acc0[4 * j4 + 2], acc0[4 * j4 + 3]);
    *reinterpret_cast<float4*>(&sacc[wv][1][j4][lane][0]) =
        make_float4(acc1[4 * j4], acc1[4 * j4 + 1], acc1[4 * j4 + 2], acc1[4 * j4 + 3]);
  }
  __syncthreads();
  int kt = wv & 1, ot = wv >> 1;
  fx16 tot;
#pragma unroll
  for (int j4 = 0; j4 < 4; ++j4) {
    float4 a0 = *reinterpret_cast<const float4*>(&sacc[0][kt][j4][lane][0]);
    float4 a1 = *reinterpret_cast<const float4*>(&sacc[1][kt][j4][lane][0]);
    float4 a2 = *reinterpret_cast<const float4*>(&sacc[2][kt][j4][lane][0]);
    float4 a3 = *reinterpret_cast<const float4*>(&sacc[3][kt][j4][lane][0]);
    tot[4 * j4]     = (a0.x + a1.x) + (a2.x + a3.x);
    tot[4 * j4 + 1] = (a0.y + a1.y) + (a2.y + a3.y);
    tot[4 * j4 + 2] = (a0.z + a1.z) + (a2.z + a3.z);
    tot[4 * j4 + 3] = (a0.w + a1.w) + (a2.w + a3.w);
  }
  bf8_t Ob0, Ob1;
#pragma unroll
  for (int j = 0; j < 8; ++j) { Ob0[j] = (__bf16)tot[j]; Ob1[j] = (__bf16)tot[8 + j]; }
  const unsigned short* wb = Wop + (ot * 32 + l31) * 32 + half * 8;
  bf8_t Aw0 = *reinterpret_cast<const bf8_t*>(wb);
  bf8_t Aw1 = *reinterpret_cast<const bf8_t*>(wb + 16);
  fx16 y = __builtin_amdgcn_mfma_f32_32x32x16_bf16(Aw0, Ob0, z, 0, 0, 0);
  y = __builtin_amdgcn_mfma_f32_32x32x16_bf16(Aw1, Ob1, y, 0, 0, 0);
  float g = gamma[0];
  int k = kbase + kt * 32 + l31;
  const float* xp = x + (size_t)b * 64 * 16384 + k;
  float* op = out + (size_t)b * 64 * 16384 + k;
#pragma unroll
  for (int r0 = 0; r0 < 16; ++r0) {
    int row = (r0 & 3) + 8 * (r0 >> 2) + 4 * half + ot * 32;
    op[(size_t)row * 16384] = fmaf(g, y[r0], xp[(size_t)row * 16384]);
  }
}

// ---------------------------------------------------------------------------
extern "C" void kernel_launch(void* const* d_in, const int* in_sizes, int n_in,
                              void* d_out, int out_size, void* d_ws, size_t ws_size,
                              hipStream_t stream) {
  const float* x     = (const float*)d_in[0];
  const float* Wq    = (const float*)d_in[1];
  const float* Wk    = (const float*)d_in[2];
  const float* Wv    = (const float*)d_in[3];
  const float* Wo    = (const float*)d_in[4];
  const float* gamma = (const float*)d_in[5];
  float* out = (float*)d_out;
  char* ws = (char*)d_ws;
  // workspace layout (bytes)
  unsigned short* Qp  = (unsigned short*)(ws + 0);        // 2 MB
  unsigned short* KpB = (unsigned short*)(ws + 2097152);  // 512 KB
  float*          Vp  = (float*)(ws + 2621440);           // 2 MB
  unsigned short* Vpp = (unsigned short*)(ws + 4718592);  // 1 MB
  float*          Ls  = (float*)(ws + 5767168);           // 64 KB
  unsigned short* Wop = (unsigned short*)(ws + 5832704);  // 4 KB

  k_qkv <<<dim3(256),  dim3(256),  0, stream>>>(x, Wq, Wk, Wv, Qp, KpB, Vp);
  k_lsum<<<dim3(256),  dim3(1024), 0, stream>>>(Qp, KpB, Ls);
  k_pack<<<dim3(65),   dim3(256),  0, stream>>>(Vp, Ls, Wo, Vpp, Wop);
  k_attn<<<dim3(1024), dim3(256),  0, stream>>>(Qp, KpB, Vpp, Wop, x, gamma, out);
}

// Round 5
// 149.835 us; speedup vs baseline: 1.6639x; 1.1214x over previous
//
#include <hip/hip_runtime.h>
#include <cstdint>
#include <cstddef>

// ---------------------------------------------------------------------------
// SelfAttention (b=4, C=64, 128x128) — MFMA bf16, round 5.
// Math identical to rounds 2-4 (no-max softmax; pi-permuted Vpp/Wop so MFMA
// C-layout feeds the next MFMA B-operand by direct bitcast).
// Round-5:
//   k_qkv rewritten: x-tile staged in LDS (contiguous row-pair strips),
//     weights via wave-uniform broadcast reads, thread=(pooled cell, rowgroup)
//     so 2x2 maxpool is in-thread. Wo pack folded in (block 256).
//   k_lsum: Vpp pack fused into its epilogue (k_pack kernel removed).
//   k_attn: 512-thr blocks (8 waves, f split 8-ways) -> 32 waves/CU;
//     two-phase fp32 LDS reduction keeps LDS at 32 KB.
// ---------------------------------------------------------------------------

#define LOG2E 1.44269504088896340736f

typedef __attribute__((ext_vector_type(8)))  __bf16 bf8_t;
typedef __attribute__((ext_vector_type(16))) float  fx16;

__device__ __forceinline__ unsigned short f2bf(float f) {
  unsigned int u = __builtin_bit_cast(unsigned int, f);
  u += 0x7FFFu + ((u >> 16) & 1u);   // round-nearest-even
  return (unsigned short)(u >> 16);
}
__device__ __forceinline__ unsigned int pk2(unsigned short lo, unsigned short hi) {
  return (unsigned int)lo | ((unsigned int)hi << 16);
}
// involution permutation on a 16-group: swap middle two quads
__device__ __forceinline__ int pi16(int s) {
  int m = (s >> 2) & 3;
  return (m == 1 || m == 2) ? (s ^ 12) : s;
}
__device__ __forceinline__ float max4(const float* a) {
  return fmaxf(fmaxf(a[0], a[1]), fmaxf(a[2], a[3]));
}

#if __has_builtin(__builtin_amdgcn_exp2f)
#define EXP2F __builtin_amdgcn_exp2f
#else
#define EXP2F exp2f
#endif

// ----------------------- K1: fused q/k/v (one x pass) -----------------------
// grid 257: blocks 0..255 = (b, frow); block 256 packs Wo.
// Block: 4 waves; wave rg owns output rows 12rg..12rg+11; lane = pooled cell
// fc (64 cells of pooled row frow). Thread computes its 12 rows at the 4
// spatial positions of its cell (rows 2frow,2frow+1 x cols 2fc,2fc+1),
// pools k/v rows in-thread, writes q for all 4 positions.
__global__ void __launch_bounds__(256) k_qkv(const float* __restrict__ x,
                                             const float* __restrict__ Wq,
                                             const float* __restrict__ Wk,
                                             const float* __restrict__ Wv,
                                             const float* __restrict__ Wo,
                                             unsigned short* __restrict__ Qp,
                                             unsigned short* __restrict__ KpB,
                                             float* __restrict__ Vp,
                                             unsigned short* __restrict__ Wop) {
  if (blockIdx.x == 256) {                         // Wo -> bf16, pi on c-cols
    for (int i = threadIdx.x; i < 2048; i += 256) {
      int c = i & 31;
      Wop[i] = f2bf(Wo[(i & ~31) | (c & 16) | pi16(c & 15)]);
    }
    return;
  }
  __shared__ float ws[48][64];                     // [row][c]: q 0-7, k 8-15, v 16-47
  __shared__ float xs[16][256];                    // c-chunk x row-pair strip
  int t = threadIdx.x;
  for (int i = t; i < 512; i += 256) {
    ws[i >> 6][i & 63] = Wq[i];
    ws[8 + (i >> 6)][i & 63] = Wk[i];
  }
  for (int i = t; i < 2048; i += 256) ws[16 + (i >> 6)][i & 63] = Wv[i];
  int b = blockIdx.x >> 6, frow = blockIdx.x & 63;
  int rg = t >> 6, fc = t & 63;
  const float* xb = x + (size_t)b * (64 * 16384) + frow * 256;
  float acc[12][4];
#pragma unroll
  for (int j = 0; j < 12; ++j)
#pragma unroll
    for (int p = 0; p < 4; ++p) acc[j][p] = 0.f;
  int cl = t >> 4, seg = t & 15;                   // staging role
  for (int cc = 0; cc < 4; ++cc) {
    __syncthreads();                               // xs free (covers ws on cc=0)
    const float4* src =
        reinterpret_cast<const float4*>(xb + (size_t)(cc * 16 + cl) * 16384 + seg * 16);
    float4* dst = reinterpret_cast<float4*>(&xs[cl][seg * 16]);
#pragma unroll
    for (int j = 0; j < 4; ++j) dst[j] = src[j];
    __syncthreads();
#pragma unroll
    for (int c16 = 0; c16 < 16; ++c16) {
      int c = cc * 16 + c16;
      float2 xa = *reinterpret_cast<const float2*>(&xs[c16][2 * fc]);
      float2 xbv = *reinterpret_cast<const float2*>(&xs[c16][128 + 2 * fc]);
#pragma unroll
      for (int j = 0; j < 12; ++j) {
        float w = ws[12 * rg + j][c];              // wave-uniform -> broadcast
        acc[j][0] = fmaf(w, xa.x, acc[j][0]);
        acc[j][1] = fmaf(w, xa.y, acc[j][1]);
        acc[j][2] = fmaf(w, xbv.x, acc[j][2]);
        acc[j][3] = fmaf(w, xbv.y, acc[j][3]);
      }
    }
  }
  size_t idx = (size_t)b * 4096 + frow * 64 + fc;
  uint4 z4; z4.x = z4.y = z4.z = z4.w = 0u;
  if (rg == 0) {
    // q rows 0-7, per position
#pragma unroll
    for (int p = 0; p < 4; ++p) {
      int kpos = frow * 256 + (p >> 1) * 128 + 2 * fc + (p & 1);
      uint4 qa;
      qa.x = pk2(f2bf(acc[0][p]), f2bf(acc[1][p]));
      qa.y = pk2(f2bf(acc[2][p]), f2bf(acc[3][p]));
      qa.z = pk2(f2bf(acc[4][p]), f2bf(acc[5][p]));
      qa.w = pk2(f2bf(acc[6][p]), f2bf(acc[7][p]));
      uint4* qdst = reinterpret_cast<uint4*>(Qp + ((size_t)b * 16384 + kpos) * 16);
      qdst[0] = qa; qdst[1] = z4;
    }
    // k chans 0-3 (rows 8-11), pooled
    uint2 kw;
    kw.x = pk2(f2bf(max4(acc[8]) * LOG2E), f2bf(max4(acc[9]) * LOG2E));
    kw.y = pk2(f2bf(max4(acc[10]) * LOG2E), f2bf(max4(acc[11]) * LOG2E));
    *reinterpret_cast<uint2*>(KpB + idx * 16) = kw;
  } else if (rg == 1) {
    // k chans 4-7 (rows 12-15) + zero pad slots 8-15
    uint2 kw;
    kw.x = pk2(f2bf(max4(acc[0]) * LOG2E), f2bf(max4(acc[1]) * LOG2E));
    kw.y = pk2(f2bf(max4(acc[2]) * LOG2E), f2bf(max4(acc[3]) * LOG2E));
    *reinterpret_cast<uint2*>(KpB + idx * 16 + 4) = kw;
    *reinterpret_cast<uint4*>(KpB + idx * 16 + 8) = z4;
    // v chans 0-7 (rows 16-23), pooled
    float* vd = Vp + idx * 32;
    *reinterpret_cast<float4*>(vd) =
        make_float4(max4(acc[4]), max4(acc[5]), max4(acc[6]), max4(acc[7]));
    *reinterpret_cast<float4*>(vd + 4) =
        make_float4(max4(acc[8]), max4(acc[9]), max4(acc[10]), max4(acc[11]));
  } else {
    // rg2: v chans 8-19 (rows 24-35); rg3: v chans 20-31 (rows 36-47)
    float* vd = Vp + idx * 32 + (rg == 2 ? 8 : 20);
#pragma unroll
    for (int j4 = 0; j4 < 3; ++j4)
      *reinterpret_cast<float4*>(vd + 4 * j4) =
          make_float4(max4(acc[4 * j4]), max4(acc[4 * j4 + 1]),
                      max4(acc[4 * j4 + 2]), max4(acc[4 * j4 + 3]));
  }
}

// ----------------- K2: l = sum exp2(S2)  +  fused Vpp pack ------------------
// block = 1024 thr (16 waves) per (b, f-group pair of 64 rows); each wave
// owns a 1024-k slice; one Q fragment load feeds 2 MFMAs (FB=2).
// Epilogue: L -> Linv, then Vpp[b][c][f'] = bf16(Vp[b][pi(f)][c] * Linv).
__global__ void __launch_bounds__(1024) k_lsum(const unsigned short* __restrict__ Qp,
                                               const unsigned short* __restrict__ KpB,
                                               const float* __restrict__ Vp,
                                               unsigned short* __restrict__ Vpp) {
  int b = blockIdx.x >> 6, g = blockIdx.x & 63;
  int wv = threadIdx.x >> 6, lane = threadIdx.x & 63;
  int half = lane >> 5, l31 = lane & 31;
  const unsigned short* kb =
      KpB + ((size_t)(b * 4096 + g * 64 + l31)) * 16 + half * 8;
  bf8_t A0 = *reinterpret_cast<const bf8_t*>(kb);
  bf8_t A1 = *reinterpret_cast<const bf8_t*>(kb + 32 * 16);
  const unsigned short* qbase = Qp + ((size_t)b * 16384) * 16 + half * 8;
  fx16 z;
#pragma unroll
  for (int i = 0; i < 16; ++i) z[i] = 0.f;
  float l[32];
#pragma unroll
  for (int i = 0; i < 32; ++i) l[i] = 0.f;
  int t0 = wv * 32;                                // wave's first 32-k chunk
  bf8_t B = *reinterpret_cast<const bf8_t*>(qbase + (size_t)(t0 * 32 + l31) * 16);
  for (int i = 0; i < 32; ++i) {
    int tn = t0 + ((i + 1) & 31);
    bf8_t nB = *reinterpret_cast<const bf8_t*>(qbase + (size_t)(tn * 32 + l31) * 16);
    fx16 s0 = __builtin_amdgcn_mfma_f32_32x32x16_bf16(A0, B, z, 0, 0, 0);
    fx16 s1 = __builtin_amdgcn_mfma_f32_32x32x16_bf16(A1, B, z, 0, 0, 0);
#pragma unroll
    for (int r0 = 0; r0 < 16; ++r0) l[r0] += EXP2F(s0[r0]);
#pragma unroll
    for (int r0 = 0; r0 < 16; ++r0) l[16 + r0] += EXP2F(s1[r0]);
    B = nB;
  }
#pragma unroll
  for (int r0 = 0; r0 < 32; ++r0)
    for (int d = 1; d < 32; d <<= 1) l[r0] += __shfl_xor(l[r0], d);
  __shared__ float sl[16][2][32];
  __shared__ float Linv[64];
  __shared__ unsigned short Tv[32][72];            // [c][f-local], +8 pad
  if (l31 == 0) {
#pragma unroll
    for (int r0 = 0; r0 < 16; ++r0) {
      int row = (r0 & 3) + 8 * (r0 >> 2) + 4 * half;
      sl[wv][0][row] = l[r0];
      sl[wv][1][row] = l[16 + r0];
    }
  }
  __syncthreads();
  if (threadIdx.x < 64) {
    int fgi = threadIdx.x >> 5, row = threadIdx.x & 31;
    float L = 0.f;
#pragma unroll
    for (int w2 = 0; w2 < 16; ++w2) L += sl[w2][fgi][row];
    Linv[threadIdx.x] = 1.0f / L;
  }
  __syncthreads();
  if (threadIdx.x < 512) {                         // scale + pi-transpose
    int floc = threadIdx.x >> 3, c4 = (threadIdx.x & 7) * 4;
    float4 v = *reinterpret_cast<const float4*>(
        Vp + ((size_t)(b * 4096 + g * 64 + floc)) * 32 + c4);
    float s = Linv[floc];
    int dst = (floc & ~15) | pi16(floc & 15);
    Tv[c4][dst]     = f2bf(v.x * s);
    Tv[c4 + 1][dst] = f2bf(v.y * s);
    Tv[c4 + 2][dst] = f2bf(v.z * s);
    Tv[c4 + 3][dst] = f2bf(v.w * s);
  }
  __syncthreads();
  if (threadIdx.x < 256) {
    int c = threadIdx.x >> 3, u = threadIdx.x & 7;
    uint4 val = *reinterpret_cast<const uint4*>(&Tv[c][u * 8]);
    *reinterpret_cast<uint4*>(Vpp + ((size_t)(b * 32 + c)) * 4096 + g * 64 + u * 8) = val;
  }
}

// ------------------------- K3: attention + project --------------------------
// block = 512 thr (8 waves) per 64-k pair of tiles; waves split f 8-ways
// (16 chunks each), KB=2 per wave. Two-phase fp32 LDS reduction (32 KB),
// waves 0-3 do the (kt, ot) Wo epilogue.
__global__ void __launch_bounds__(512) k_attn(const unsigned short* __restrict__ Qp,
                                              const unsigned short* __restrict__ KpB,
                                              const unsigned short* __restrict__ Vpp,
                                              const unsigned short* __restrict__ Wop,
                                              const float* __restrict__ x,
                                              const float* __restrict__ gamma,
                                              float* __restrict__ out) {
  int b = blockIdx.x >> 8, kp = blockIdx.x & 255;
  int wv = threadIdx.x >> 6, lane = threadIdx.x & 63;
  int half = lane >> 5, l31 = lane & 31;
  int kbase = kp * 64;
  const unsigned short* qb = Qp + ((size_t)b * 16384 + kbase + l31) * 16 + half * 8;
  bf8_t Bq0 = *reinterpret_cast<const bf8_t*>(qb);
  bf8_t Bq1 = *reinterpret_cast<const bf8_t*>(qb + 32 * 16);
  fx16 z;
#pragma unroll
  for (int i = 0; i < 16; ++i) z[i] = 0.f;
  fx16 acc0 = z, acc1 = z;
  const unsigned short* kpB = KpB + ((size_t)b * 4096 + l31) * 16 + half * 8;
  const unsigned short* vpB = Vpp + ((size_t)(b * 32 + l31)) * 4096 + half * 8;
  int c0 = wv * 16;                                // wave's first f-chunk
  int f0 = c0 * 32;
  bf8_t Ak  = *reinterpret_cast<const bf8_t*>(kpB + (size_t)f0 * 16);
  bf8_t Av0 = *reinterpret_cast<const bf8_t*>(vpB + f0);
  bf8_t Av1 = *reinterpret_cast<const bf8_t*>(vpB + f0 + 16);
  for (int fc = 0; fc < 16; ++fc) {
    int f1 = (c0 + ((fc + 1) & 15)) * 32;          // wraps within wave's range
    bf8_t nAk  = *reinterpret_cast<const bf8_t*>(kpB + (size_t)f1 * 16);
    bf8_t nAv0 = *reinterpret_cast<const bf8_t*>(vpB + f1);
    bf8_t nAv1 = *reinterpret_cast<const bf8_t*>(vpB + f1 + 16);
    fx16 s0 = __builtin_amdgcn_mfma_f32_32x32x16_bf16(Ak, Bq0, z, 0, 0, 0);
    fx16 s1 = __builtin_amdgcn_mfma_f32_32x32x16_bf16(Ak, Bq1, z, 0, 0, 0);
    bf8_t P00, P01, P10, P11;
#pragma unroll
    for (int j = 0; j < 8; ++j) {
      P00[j] = (__bf16)EXP2F(s0[j]);
      P01[j] = (__bf16)EXP2F(s0[8 + j]);
    }
#pragma unroll
    for (int j = 0; j < 8; ++j) {
      P10[j] = (__bf16)EXP2F(s1[j]);
      P11[j] = (__bf16)EXP2F(s1[8 + j]);
    }
    acc0 = __builtin_amdgcn_mfma_f32_32x32x16_bf16(Av0, P00, acc0, 0, 0, 0);
    acc1 = __builtin_amdgcn_mfma_f32_32x32x16_bf16(Av0, P10, acc1, 0, 0, 0);
    acc0 = __builtin_amdgcn_mfma_f32_32x32x16_bf16(Av1, P01, acc0, 0, 0, 0);
    acc1 = __builtin_amdgcn_mfma_f32_32x32x16_bf16(Av1, P11, acc1, 0, 0, 0);
    Ak = nAk; Av0 = nAv0; Av1 = nAv1;
  }
  // two-phase reduction: waves 4-7 deposit, waves 0-3 merge pairwise, then
  // waves 0-3 sum the 4 pairwise slots.  [slot][kt][j4][lane][4] fp32, 32 KB.
  __shared__ float sacc[4][2][4][64][4];
  if (wv >= 4) {
    int s = wv - 4;
#pragma unroll
    for (int j4 = 0; j4 < 4; ++j4) {
      *reinterpret_cast<float4*>(&sacc[s][0][j4][lane][0]) =
          make_float4(acc0[4 * j4], acc0[4 * j4 + 1], acc0[4 * j4 + 2], acc0[4 * j4 + 3]);
      *reinterpret_cast<float4*>(&sacc[s][1][j4][lane][0]) =
          make_float4(acc1[4 * j4], acc1[4 * j4 + 1], acc1[4 * j4 + 2], acc1[4 * j4 + 3]);
    }
  }
  __syncthreads();
  if (wv < 4) {
#pragma unroll
    for (int j4 = 0; j4 < 4; ++j4) {
      float4 p0 = *reinterpret_cast<const float4*>(&sacc[wv][0][j4][lane][0]);
      float4 p1 = *reinterpret_cast<const float4*>(&sacc[wv][1][j4][lane][0]);
      p0.x += acc0[4 * j4]; p0.y += acc0[4 * j4 + 1];
      p0.z += acc0[4 * j4 + 2]; p0.w += acc0[4 * j4 + 3];
      p1.x += acc1[4 * j4]; p1.y += acc1[4 * j4 + 1];
      p1.z += acc1[4 * j4 + 2]; p1.w += acc1[4 * j4 + 3];
      *reinterpret_cast<float4*>(&sacc[wv][0][j4][lane][0]) = p0;
      *reinterpret_cast<float4*>(&sacc[wv][1][j4][lane][0]) = p1;
    }
  }
  __syncthreads();
  if (wv >= 4) return;
  int kt = wv & 1, ot = wv >> 1;
  fx16 tot;
#pragma unroll
  for (int j4 = 0; j4 < 4; ++j4) {
    float4 a0 = *reinterpret_cast<const float4*>(&sacc[0][kt][j4][lane][0]);
    float4 a1 = *reinterpret_cast<const float4*>(&sacc[1][kt][j4][lane][0]);
    float4 a2 = *reinterpret_cast<const float4*>(&sacc[2][kt][j4][lane][0]);
    float4 a3 = *reinterpret_cast<const float4*>(&sacc[3][kt][j4][lane][0]);
    tot[4 * j4]     = (a0.x + a1.x) + (a2.x + a3.x);
    tot[4 * j4 + 1] = (a0.y + a1.y) + (a2.y + a3.y);
    tot[4 * j4 + 2] = (a0.z + a1.z) + (a2.z + a3.z);
    tot[4 * j4 + 3] = (a0.w + a1.w) + (a2.w + a3.w);
  }
  bf8_t Ob0, Ob1;
#pragma unroll
  for (int j = 0; j < 8; ++j) { Ob0[j] = (__bf16)tot[j]; Ob1[j] = (__bf16)tot[8 + j]; }
  const unsigned short* wb = Wop + (ot * 32 + l31) * 32 + half * 8;
  bf8_t Aw0 = *reinterpret_cast<const bf8_t*>(wb);
  bf8_t Aw1 = *reinterpret_cast<const bf8_t*>(wb + 16);
  fx16 y = __builtin_amdgcn_mfma_f32_32x32x16_bf16(Aw0, Ob0, z, 0, 0, 0);
  y = __builtin_amdgcn_mfma_f32_32x32x16_bf16(Aw1, Ob1, y, 0, 0, 0);
  float g = gamma[0];
  int k = kbase + kt * 32 + l31;
  const float* xp = x + (size_t)b * 64 * 16384 + k;
  float* op = out + (size_t)b * 64 * 16384 + k;
#pragma unroll
  for (int r0 = 0; r0 < 16; ++r0) {
    int row = (r0 & 3) + 8 * (r0 >> 2) + 4 * half + ot * 32;
    op[(size_t)row * 16384] = fmaf(g, y[r0], xp[(size_t)row * 16384]);
  }
}

// ---------------------------------------------------------------------------
extern "C" void kernel_launch(void* const* d_in, const int* in_sizes, int n_in,
                              void* d_out, int out_size, void* d_ws, size_t ws_size,
                              hipStream_t stream) {
  const float* x     = (const float*)d_in[0];
  const float* Wq    = (const float*)d_in[1];
  const float* Wk    = (const float*)d_in[2];
  const float* Wv    = (const float*)d_in[3];
  const float* Wo    = (const float*)d_in[4];
  const float* gamma = (const float*)d_in[5];
  float* out = (float*)d_out;
  char* ws = (char*)d_ws;
  // workspace layout (bytes)
  unsigned short* Qp  = (unsigned short*)(ws + 0);        // 2 MB
  unsigned short* KpB = (unsigned short*)(ws + 2097152);  // 512 KB
  float*          Vp  = (float*)(ws + 2621440);           // 2 MB
  unsigned short* Vpp = (unsigned short*)(ws + 4718592);  // 1 MB
  unsigned short* Wop = (unsigned short*)(ws + 5767168);  // 4 KB

  k_qkv <<<dim3(257),  dim3(256),  0, stream>>>(x, Wq, Wk, Wv, Wo, Qp, KpB, Vp, Wop);
  k_lsum<<<dim3(256),  dim3(1024), 0, stream>>>(Qp, KpB, Vp, Vpp);
  k_attn<<<dim3(1024), dim3(512),  0, stream>>>(Qp, KpB, Vpp, Wop, x, gamma, out);
}